// Round 1
// baseline (361.330 us; speedup 1.0000x reference)
//
#include <hip/hip_runtime.h>
#include <math.h>

#define DFEAT 128
#define A_MAX 1024
#define ROWS_PER_BLOCK 64

// Each half-wave (32 lanes) handles one row: lane l loads float4 at col 4*l.
// A full 64-lane wave therefore reads 2 contiguous rows = 1 KiB coalesced.
__global__ __launch_bounds__(256) void icc_dist_kernel(
    const float* __restrict__ anchors,
    const float* __restrict__ Xn,
    const int*   __restrict__ seg,
    float*       __restrict__ per_anchor,  // [num_anchors] global accumulator
    int total, int num_anchors)
{
    __shared__ float acc[A_MAX];
    const int tid = threadIdx.x;
    for (int i = tid; i < A_MAX; i += 256) acc[i] = 0.0f;
    __syncthreads();

    const int lane = tid & 31;   // lane within half-wave
    const int hw   = tid >> 5;   // half-wave id within block (0..7)
    const int rowBase = blockIdx.x * ROWS_PER_BLOCK;
    const float eps = 1e-4f / (float)DFEAT;

    #pragma unroll
    for (int r = 0; r < ROWS_PER_BLOCK / 8; ++r) {
        const int row = rowBase + r * 8 + hw;
        if (row < total) {
            const int a = seg[row];  // 32 lanes same addr -> broadcast load
            const float4 x  = *reinterpret_cast<const float4*>(
                Xn + (size_t)row * DFEAT + lane * 4);
            const float4 av = *reinterpret_cast<const float4*>(
                anchors + (size_t)a * DFEAT + lane * 4);
            const float dx = x.x - av.x;
            const float dy = x.y - av.y;
            const float dz = x.z - av.z;
            const float dw = x.w - av.w;
            float sq = dx * dx + dy * dy + dz * dz + dw * dw;
            #pragma unroll
            for (int off = 16; off > 0; off >>= 1)
                sq += __shfl_down(sq, off, 32);
            if (lane == 0) {
                const float dist = sqrtf(sq + eps);
                if (a < A_MAX) atomicAdd(&acc[a], dist);          // LDS atomic
                else           atomicAdd(&per_anchor[a], dist);   // safety path
            }
        }
    }
    __syncthreads();
    // Flush block-local sums; sorted segment_ids => ~2-3 nonzero entries/block.
    for (int i = tid; i < num_anchors && i < A_MAX; i += 256) {
        const float v = acc[i];
        if (v != 0.0f) atomicAdd(&per_anchor[i], v);
    }
}

__global__ __launch_bounds__(256) void icc_final_kernel(
    const float* __restrict__ per_anchor,
    float*       __restrict__ out,
    int num_anchors, float inv_total)
{
    __shared__ float red[4];
    const int tid = threadIdx.x;
    float s = 0.0f;
    for (int i = tid; i < num_anchors; i += 256)
        s += log1pf(per_anchor[i]);
    #pragma unroll
    for (int off = 32; off > 0; off >>= 1)
        s += __shfl_down(s, off, 64);
    if ((tid & 63) == 0) red[tid >> 6] = s;
    __syncthreads();
    if (tid == 0) {
        const float t = red[0] + red[1] + red[2] + red[3];
        out[0] = t * inv_total;
    }
}

extern "C" void kernel_launch(void* const* d_in, const int* in_sizes, int n_in,
                              void* d_out, int out_size, void* d_ws, size_t ws_size,
                              hipStream_t stream) {
    const float* anchors = (const float*)d_in[0];
    const float* Xn      = (const float*)d_in[1];
    const int*   seg     = (const int*)d_in[2];
    float* out = (float*)d_out;

    const int num_anchors = in_sizes[0] / DFEAT;   // 1024
    const int total       = in_sizes[2];           // 524288

    float* per_anchor = (float*)d_ws;              // num_anchors floats
    hipMemsetAsync(per_anchor, 0, (size_t)num_anchors * sizeof(float), stream);

    const int blocks = (total + ROWS_PER_BLOCK - 1) / ROWS_PER_BLOCK;
    icc_dist_kernel<<<blocks, 256, 0, stream>>>(
        anchors, Xn, seg, per_anchor, total, num_anchors);
    icc_final_kernel<<<1, 256, 0, stream>>>(
        per_anchor, out, num_anchors, 1.0f / (float)total);
}